// Round 1
// baseline (202.096 us; speedup 1.0000x reference)
//
#include <hip/hip_runtime.h>

// DCT_18769007084406: RGB->YCbCr (1x1 conv) -> 8x8 stride-8 block DCT
// (grouped conv) -> 32x repeated (t-min)/d normalization (closed form).
//
// R3: LDS-free version. Previous R2 staged the YCbCr band in 48 KB LDS,
// which (a) capped occupancy at 3 blocks/CU (24% measured), (b) serialized
// load/compute via __syncthreads, (c) idled wave 3 of 4 in stage 2, and
// (d) ate ~4-way LDS bank conflicts (bank = (bx*8)%32).
// Counters showed VALUBusy 15%, HBM 22% -> latency-bound, not BW-bound.
//
// Now: 192-thread blocks (3 waves), wave = YCbCr channel, lane = block-col.
// Each lane reads its 8x8 block's R/G/B rows straight from global (lane bx
// reads floats [bx*8, bx*8+8) of a row -> contiguous 2 KB per wave access,
// fully coalesced), fuses the color transform in registers, does the
// separable DCT, applies the closed-form norm, stores. The 3x re-read of
// R/G/B across the 3 channel-waves of one band hits L1/L2 (same CU).
// No LDS, no barrier -> occupancy VGPR-limited (launch_bounds(192,4) caps
// at 128 VGPR = 16 waves/CU).

#define HW 512
#define CHST (HW * HW)       // channel stride in x
#define NPAIR 6144           // 32 * 192 (b, out-channel) pairs
#define EPS 1e-6f

// basis[u][i] = c(u) * cos(pi*u*(i+0.5)/8); c(0)=sqrt(1/8), c(u>0)=0.5
static constexpr float BASIS[8][8] = {
  { 0.35355339059327373f, 0.35355339059327373f, 0.35355339059327373f, 0.35355339059327373f,
    0.35355339059327373f, 0.35355339059327373f, 0.35355339059327373f, 0.35355339059327373f },
  { 0.49039264020161522f, 0.41573480615127262f, 0.27778511650980114f, 0.09754516100806412f,
   -0.09754516100806412f,-0.27778511650980114f,-0.41573480615127262f,-0.49039264020161522f },
  { 0.46193976625564337f, 0.19134171618254492f,-0.19134171618254492f,-0.46193976625564337f,
   -0.46193976625564337f,-0.19134171618254492f, 0.19134171618254492f, 0.46193976625564337f },
  { 0.41573480615127262f,-0.09754516100806412f,-0.49039264020161522f,-0.27778511650980114f,
    0.27778511650980114f, 0.49039264020161522f, 0.09754516100806412f,-0.41573480615127262f },
  { 0.35355339059327373f,-0.35355339059327373f,-0.35355339059327373f, 0.35355339059327373f,
    0.35355339059327373f,-0.35355339059327373f,-0.35355339059327373f, 0.35355339059327373f },
  { 0.27778511650980114f,-0.49039264020161522f, 0.09754516100806412f, 0.41573480615127262f,
   -0.41573480615127262f,-0.09754516100806412f, 0.49039264020161522f,-0.27778511650980114f },
  { 0.19134171618254492f,-0.46193976625564337f, 0.46193976625564337f,-0.19134171618254492f,
   -0.19134171618254492f, 0.46193976625564337f,-0.46193976625564337f, 0.19134171618254492f },
  { 0.09754516100806412f,-0.27778511650980114f, 0.41573480615127262f,-0.49039264020161522f,
    0.49039264020161522f,-0.41573480615127262f, 0.27778511650980114f,-0.09754516100806412f }
};

// t_32 = a^32 * t0 - min * sum_{k=1..32} a^k, a = 1/(max-min+eps)
__global__ void precomp_norm(const float* __restrict__ max_,
                             const float* __restrict__ min_,
                             float* __restrict__ so) {
    int i = blockIdx.x * 256 + threadIdx.x;
    if (i >= NPAIR) return;
    float mn = min_[i], mx = max_[i];
    float d = mx - mn + EPS;
    float a = 1.0f / d;
    float a2 = a * a, a4 = a2 * a2, a8 = a4 * a4, a16 = a8 * a8, a32 = a16 * a16;
    float geo = a * (1.0f - a32) / (1.0f - a);   // sum_{k=1..32} a^k
    so[2 * i]     = a32;
    so[2 * i + 1] = -mn * geo;
}

template <bool USE_WS>
__global__ __launch_bounds__(192, 4)
void dct_kernel(const float* __restrict__ x,
                const float* __restrict__ ycbcr_w,
                const float* __restrict__ so,
                const float* __restrict__ max_,
                const float* __restrict__ min_,
                float* __restrict__ out) {
    const int b  = blockIdx.x >> 6;        // batch
    const int by = blockIdx.x & 63;        // block-row
    const int t  = threadIdx.x;
    const int c  = t >> 6;                 // wave = YCbCr channel
    const int bx = t & 63;                 // lane = block-col -> coalesced

    // channel weights (wave-uniform)
    const float wr = ycbcr_w[3 * c];
    const float wg = ycbcr_w[3 * c + 1];
    const float wb = ycbcr_w[3 * c + 2];

    // this lane's 8x8 block: rows i at base + i*HW, cols [0,8)
    const float* base = x + (size_t)(b * 3) * CHST + (size_t)(by * 8) * HW + bx * 8;

    float tmp[8][8];   // tmp[u][j] = sum_i basis[u][i] * y[i][j]
#pragma unroll
    for (int u = 0; u < 8; ++u)
#pragma unroll
        for (int j = 0; j < 8; ++j) tmp[u][j] = 0.0f;

#pragma unroll
    for (int i = 0; i < 8; ++i) {
        const float* rp = base + i * HW;
        // lane bx reads 32B at bx*32 -> wave covers a contiguous 2KB row
        float4 r0 = *(const float4*)(rp);
        float4 r1 = *(const float4*)(rp + 4);
        float4 g0 = *(const float4*)(rp + CHST);
        float4 g1 = *(const float4*)(rp + CHST + 4);
        float4 b0 = *(const float4*)(rp + 2 * CHST);
        float4 b1 = *(const float4*)(rp + 2 * CHST + 4);

        float y[8];
        y[0] = fmaf(wr, r0.x, fmaf(wg, g0.x, wb * b0.x));
        y[1] = fmaf(wr, r0.y, fmaf(wg, g0.y, wb * b0.y));
        y[2] = fmaf(wr, r0.z, fmaf(wg, g0.z, wb * b0.z));
        y[3] = fmaf(wr, r0.w, fmaf(wg, g0.w, wb * b0.w));
        y[4] = fmaf(wr, r1.x, fmaf(wg, g1.x, wb * b1.x));
        y[5] = fmaf(wr, r1.y, fmaf(wg, g1.y, wb * b1.y));
        y[6] = fmaf(wr, r1.z, fmaf(wg, g1.z, wb * b1.z));
        y[7] = fmaf(wr, r1.w, fmaf(wg, g1.w, wb * b1.w));

#pragma unroll
        for (int u = 0; u < 8; ++u) {
            const float bu = BASIS[u][i];
#pragma unroll
            for (int j = 0; j < 8; ++j)
                tmp[u][j] = fmaf(bu, y[j], tmp[u][j]);
        }
    }

    const int obase = b * 192 + c * 64;    // first output channel index
    float* op = out + ((size_t)obase * 64 + by) * 64 + bx;
    const float2* sop = (const float2*)so + obase;   // (scale, offset) pairs

#pragma unroll
    for (int u = 0; u < 8; ++u) {
#pragma unroll
        for (int v = 0; v < 8; ++v) {
            float acc = tmp[u][0] * BASIS[v][0];
#pragma unroll
            for (int j = 1; j < 8; ++j)
                acc = fmaf(tmp[u][j], BASIS[v][j], acc);
            const int k = u * 8 + v;
            float s, o;
            if (USE_WS) {
                float2 p = sop[k];                 // wave-uniform, L1-hit
                s = p.x;
                o = p.y;
            } else {
                float mn = min_[obase + k], mx = max_[obase + k];
                float d  = mx - mn + EPS;
                float a  = 1.0f / d;
                float a2 = a * a, a4 = a2 * a2, a8 = a4 * a4, a16 = a8 * a8, a32 = a16 * a16;
                s = a32;
                o = -mn * (a * (1.0f - a32) / (1.0f - a));
            }
            op[(size_t)k * 4096] = fmaf(s, acc, o);  // lanes consecutive in bx
        }
    }
}

extern "C" void kernel_launch(void* const* d_in, const int* in_sizes, int n_in,
                              void* d_out, int out_size, void* d_ws, size_t ws_size,
                              hipStream_t stream) {
    const float* x    = (const float*)d_in[0];
    const float* max_ = (const float*)d_in[1];
    const float* min_ = (const float*)d_in[2];
    const float* yw   = (const float*)d_in[3];
    float* out = (float*)d_out;
    float* so  = (float*)d_ws;

    const bool use_ws = (ws_size >= (size_t)NPAIR * 2 * sizeof(float));
    if (use_ws) {
        precomp_norm<<<(NPAIR + 255) / 256, 256, 0, stream>>>(max_, min_, so);
        dct_kernel<true><<<32 * 64, 192, 0, stream>>>(x, yw, so, max_, min_, out);
    } else {
        dct_kernel<false><<<32 * 64, 192, 0, stream>>>(x, yw, nullptr, max_, min_, out);
    }
}